// Round 6
// baseline (358.368 us; speedup 1.0000x reference)
//
#include <hip/hip_runtime.h>
#include <stdint.h>

// ---------------------------------------------------------------------------
// LogSparse attention (B=4, T=2048, E=512, H=8, head_dim=64, q/k width e=512)
//   0) convert x, w_qk to bf16; transpose+convert w_v, w_proj to [N][K] bf16
//   1) QK = x @ w_qk^T           (bf16 MFMA GEMM, C bf16 [8192][8192])
//   2) V  = x @ w_v + b_v        (bf16 MFMA GEMM, stored transposed [b,h,d,t])
//   3) flash attention, analytic log-sparse mask -> ctx bf16 [8192][512]
//      - q-tile 128, 4 waves x 32 q-rows (halves LDS-read/FLOP vs 16 rows)
//      - K: 4 x 16KB LDS buffers, counted-vmcnt pipeline (stage 3 ahead)
//      - no-max softmax (data-safe), row-sum via all-ones MFMA column
//      - V global->reg, P via swizzled wave-private LDS
//   4) out = ctx @ w_proj + b_proj (f32 out)
// ---------------------------------------------------------------------------

typedef __attribute__((ext_vector_type(8))) short short8;
typedef __attribute__((ext_vector_type(4))) float f32x4;
typedef __attribute__((ext_vector_type(4))) unsigned short us4;

__device__ __forceinline__ f32x4 fzero4() { f32x4 z = {0.f, 0.f, 0.f, 0.f}; return z; }

__device__ __forceinline__ unsigned short f2bf(float f) {  // RNE f32->bf16
  unsigned u = __float_as_uint(f);
  u += 0x7fff + ((u >> 16) & 1);
  return (unsigned short)(u >> 16);
}

__device__ __forceinline__ void gload_lds16(const void* g, void* l) {
  __builtin_amdgcn_global_load_lds((const __attribute__((address_space(1))) void*)g,
                                   (__attribute__((address_space(3))) void*)l, 16, 0, 0);
}

// bijective XCD swizzle (nwg % 8 == 0 for all our grids)
__device__ __forceinline__ int xcd_swizzle(int flat, int nwg) {
  const int cpx = nwg >> 3;
  return (flat & 7) * cpx + (flat >> 3);
}

// ---------------------------------------------------------------------------
// GEMM: C[M,N] = A[M,K] * B[N,K]^T  (A,B bf16 row-major, K-contiguous)
// 128x128 tile, BK=32, 256 threads (4 waves, 2x2), 16x16x32 bf16 MFMA.
// EPI 0: C bf16 row-major, no bias
// EPI 1: V epilogue: bf16, +bias, stored transposed V_t[(b*512+col)][t]
// EPI 2: C f32 row-major, +bias
// ---------------------------------------------------------------------------
template <int EPI>
__global__ __launch_bounds__(256, 2) void gemm_bt(const unsigned short* __restrict__ A,
                                                  const unsigned short* __restrict__ B,
                                                  void* __restrict__ Cout,
                                                  const float* __restrict__ bias,
                                                  int M, int N, int K) {
  __shared__ unsigned short As[128 * 32];
  __shared__ unsigned short Bs[128 * 32];
  const int tid = threadIdx.x;
  const int wid = tid >> 6;
  const int lane = tid & 63;
  const int wm = wid >> 1, wn = wid & 1;
  const int nbx = (M + 127) / 128;
  const int sw = xcd_swizzle(blockIdx.y * gridDim.x + blockIdx.x, gridDim.x * gridDim.y);
  const long m0 = (long)(sw % nbx) * 128;
  const long n0 = (long)(sw / nbx) * 128;

  f32x4 acc[4][4];
#pragma unroll
  for (int i = 0; i < 4; ++i)
#pragma unroll
    for (int j = 0; j < 4; ++j) acc[i][j] = fzero4();

  const int lrow = tid >> 2;          // 0..63
  const int lcol = (tid & 3) * 8;     // 0,8,16,24
  const unsigned short* Ag = A + (m0 + lrow) * (long)K + lcol;
  const unsigned short* Bg = B + (n0 + lrow) * (long)K + lcol;
  unsigned short* Asl = As + tid * 8;
  unsigned short* Bsl = Bs + tid * 8;
  const long K64 = (long)64 * K;

  const int fr = lane & 15;
  const int fk = (lane >> 4) * 8;

  for (int k0 = 0; k0 < K; k0 += 32) {
    gload_lds16(Ag + k0, Asl);
    gload_lds16(Ag + K64 + k0, Asl + 2048);
    gload_lds16(Bg + k0, Bsl);
    gload_lds16(Bg + K64 + k0, Bsl + 2048);
    __syncthreads();
    short8 af[4], bfr[4];
#pragma unroll
    for (int i = 0; i < 4; ++i) af[i] = *(const short8*)&As[(wm * 64 + i * 16 + fr) * 32 + fk];
#pragma unroll
    for (int j = 0; j < 4; ++j) bfr[j] = *(const short8*)&Bs[(wn * 64 + j * 16 + fr) * 32 + fk];
#pragma unroll
    for (int i = 0; i < 4; ++i)
#pragma unroll
      for (int j = 0; j < 4; ++j)
        acc[i][j] = __builtin_amdgcn_mfma_f32_16x16x32_bf16(af[i], bfr[j], acc[i][j], 0, 0, 0);
    __syncthreads();
  }

  const int fg = lane >> 4;
#pragma unroll
  for (int i = 0; i < 4; ++i) {
#pragma unroll
    for (int j = 0; j < 4; ++j) {
      const long row0 = m0 + wm * 64 + i * 16 + fg * 4;  // +r
      const long col = n0 + wn * 64 + j * 16 + fr;
      if (EPI == 0) {
        unsigned short* C = (unsigned short*)Cout;
#pragma unroll
        for (int r = 0; r < 4; ++r) C[(row0 + r) * (long)N + col] = f2bf(acc[i][j][r]);
      } else if (EPI == 1) {
        unsigned short* C = (unsigned short*)Cout;
        const float bs = bias[col];
        const int b_ = (int)(row0 >> 11);
        const int t0 = (int)(row0 & 2047);
        us4 pk;
#pragma unroll
        for (int r = 0; r < 4; ++r) pk[r] = f2bf(acc[i][j][r] + bs);
        *(us4*)&C[((size_t)(b_ * 512 + col)) * 2048 + t0] = pk;  // [b,h,d][t]
      } else {
        float* C = (float*)Cout;
        const float bs = bias[col];
#pragma unroll
        for (int r = 0; r < 4; ++r) C[(row0 + r) * (long)N + col] = acc[i][j][r] + bs;
      }
    }
  }
}

// ---------------------------------------------------------------------------
// Flash attention, log-sparse mask. 512 blocks, 256 threads (4 waves).
// blk -> (bh = blk&31, qtp = 15-(blk>>5)): 128 q-rows, longest job first.
// Wave w owns rows {qtp*128 + i*64 + w*16 .. +15} for i in {0,1}.
// K: 4 chunk-buffers [64 keys][128 e], XOR-swizzled, staged 3 ahead with
// counted vmcnt (T3/T4). V: global->reg. P: wave-private swizzled LDS.
// No-max softmax; row-sum l accumulated via all-ones MFMA B operand.
// ---------------------------------------------------------------------------
#define PHASE_SYNC(N)                                       \
  asm volatile("s_waitcnt vmcnt(" #N ")" ::: "memory");     \
  asm volatile("s_barrier" ::: "memory");

#define STAGE_CHUNK(BUF, KTG, CG)                                         \
  do {                                                                    \
    const unsigned short* _src = Kg + (size_t)(KTG) * (64 * 8192) + (CG) * 128; \
    gload_lds16(_src, &Kb[BUF][tid * 8]);                                 \
    gload_lds16(_src + 16 * 8192, &Kb[BUF][2048 + tid * 8]);              \
    gload_lds16(_src + 32 * 8192, &Kb[BUF][4096 + tid * 8]);              \
    gload_lds16(_src + 48 * 8192, &Kb[BUF][6144 + tid * 8]);              \
  } while (0)

#define QK_PHASE(BUF)                                                         \
  __builtin_amdgcn_s_setprio(1);                                              \
  _Pragma("unroll") for (int e = 0; e < 4; ++e) {                             \
    _Pragma("unroll") for (int j = 0; j < 4; ++j) {                           \
      const short8 bfr = *(const short8*)&Kb[BUF][(j * 16 + fr) * 128 +       \
                                                  (((e * 4 + fg) ^ xsw) << 3)]; \
      s[0][j] = __builtin_amdgcn_mfma_f32_16x16x32_bf16(qreg[0][(BUF)*4 + e], \
                                                        bfr, s[0][j], 0, 0, 0); \
      s[1][j] = __builtin_amdgcn_mfma_f32_16x16x32_bf16(qreg[1][(BUF)*4 + e], \
                                                        bfr, s[1][j], 0, 0, 0); \
    }                                                                         \
  }                                                                           \
  __builtin_amdgcn_s_setprio(0);

__global__ __launch_bounds__(256, 2) void flash_attn(const unsigned short* __restrict__ QK,
                                                     const unsigned short* __restrict__ Vt,
                                                     unsigned short* __restrict__ ctx) {
  __shared__ unsigned short Kb[4][64 * 128];   // 4 x 16 KB
  __shared__ unsigned short Plds[4][32 * 64];  // 16 KB, per-wave

  const int tid = threadIdx.x, wid = tid >> 6, lane = tid & 63;
  const int fr = lane & 15, fg = lane >> 4;
  const int xsw = fr & 7;
  const int blk = blockIdx.x;
  const int qtp = 15 - (blk >> 5);  // longest-first
  const int bh = blk & 31;
  const int b = bh >> 3, h = bh & 7;
  const int nkt = 2 * qtp + 2;

  // ---- Q fragments -> registers: 2 groups x 16 e-steps (128 VGPR)
  short8 qreg[2][16];
  {
    const unsigned short* qp =
        QK + (size_t)(b * 2048 + qtp * 128 + wid * 16 + fr) * 8192 + h * 512 + fg * 8;
#pragma unroll
    for (int i = 0; i < 2; ++i)
#pragma unroll
      for (int e = 0; e < 16; ++e)
        qreg[i][e] = *(const short8*)(qp + (size_t)i * 64 * 8192 + e * 32);
  }

  // ---- mask bitmaps (bit r*4+j); circulant => identical for both i-groups
  unsigned m_gen = 0xFFFFu, m_t0 = 0xFFFFu, m_diag = 0u;
  {
    const int lrow = wid * 16 + fg * 4;  // row within 64-aligned tile
    if (qtp <= 2) {                      // rows < 384: plain causal
#pragma unroll
      for (int r = 0; r < 4; ++r)
#pragma unroll
        for (int j = 0; j < 4; ++j)
          if (j * 16 + fr <= lrow + r) m_diag |= 1u << (r * 4 + j);
    } else {
      m_gen = 0; m_t0 = 0;
      const unsigned long long SBITS = 0x20002022FFull;  // t in {0..7,9,13,21,37}
#pragma unroll
      for (int r = 0; r < 4; ++r) {
        const int irow = qtp * 128 + lrow + r;
#pragma unroll
        for (int j = 0; j < 4; ++j) {
          const int c = j * 16 + fr;
          const int t = (irow - c) & 63;
          const unsigned g = (unsigned)((SBITS >> t) & 1ull);
          const unsigned bit = 1u << (r * 4 + j);
          if (g) m_gen |= bit;
          if ((c + t >= 5) ? (g != 0) : (t >= 1)) m_t0 |= bit;  // terminal rule
          if (g && c <= lrow + r) m_diag |= bit;
        }
      }
    }
  }

  f32x4 o[2][4], ol[2];
#pragma unroll
  for (int i = 0; i < 2; ++i) {
    ol[i] = fzero4();
#pragma unroll
    for (int j = 0; j < 4; ++j) o[i][j] = fzero4();
  }

  short8 ones;
#pragma unroll
  for (int z = 0; z < 8; ++z) ones[z] = (short)0x3F80;  // bf16 1.0

  // ---- K staging base (pre-swizzled global source; LDS dest linear)
  const int sslot = (tid & 15) ^ ((tid >> 4) & 7);
  const unsigned short* Kg =
      QK + (size_t)(b * 2048 + (tid >> 4)) * 8192 + 4096 + h * 512 + sslot * 8;

  // prologue: chunks 0,1,2 -> buffers 0,1,2
  STAGE_CHUNK(0, 0, 0);
  STAGE_CHUNK(1, 0, 1);
  STAGE_CHUNK(2, 0, 2);

  const int D0 = 2 * qtp;

  for (int kt = 0; kt < nkt; ++kt) {
    f32x4 s[2][4];
#pragma unroll
    for (int i = 0; i < 2; ++i)
#pragma unroll
      for (int j = 0; j < 4; ++j) s[i][j] = fzero4();
    short8 vreg[2][4];

    // ---- phase c0 : compute buf0, stage chunk (kt,3)->buf3
    PHASE_SYNC(8);
    STAGE_CHUNK(3, kt, 3);
    QK_PHASE(0);

    // ---- phase c1 : compute buf1, stage chunk (kt+1,0)->buf0 (dummy at tail)
    PHASE_SYNC(8);
    {
      int ktg = kt + 1; if (ktg >= nkt) --ktg;
      STAGE_CHUNK(0, ktg, 0);
    }
    QK_PHASE(1);

    // ---- phase c2 : V loads, compute buf2, stage chunk (kt+1,1)->buf1
    PHASE_SYNC(8);
#pragma unroll
    for (int ks = 0; ks < 2; ++ks)
#pragma unroll
      for (int jd = 0; jd < 4; ++jd)
        vreg[ks][jd] = *(const short8*)(Vt + (size_t)(bh * 64 + jd * 16 + fr) * 2048 +
                                        kt * 64 + ks * 32 + fg * 8);
    {
      int ktg = kt + 1; if (ktg >= nkt) --ktg;
      STAGE_CHUNK(1, ktg, 1);
    }
    QK_PHASE(2);

    // ---- phase c3 : compute buf3, stage chunk (kt+1,2)->buf2
    PHASE_SYNC(16);
    {
      int ktg = kt + 1; if (ktg >= nkt) --ktg;
      STAGE_CHUNK(2, ktg, 2);
    }
    QK_PHASE(3);

    // ---- no-max softmax: P = exp2(s * scale * log2e), masked -> 0
    const unsigned mbase = (kt == 0) ? m_t0 : m_gen;
    unsigned mm[2];
    mm[0] = (kt < D0) ? mbase : ((kt == D0) ? (mbase & m_diag) : 0u);
    mm[1] = (kt <= D0) ? mbase : (mbase & m_diag);
#pragma unroll
    for (int i = 0; i < 2; ++i) {
#pragma unroll
      for (int r = 0; r < 4; ++r) {
#pragma unroll
        for (int j = 0; j < 4; ++j) {
          float v = s[i][j][r] * 0.18033688f;  // 0.125 * log2(e)
          v = ((mm[i] >> (r * 4 + j)) & 1u) ? v : -1e30f;
          const float p = __builtin_amdgcn_exp2f(v);
          Plds[wid][(i * 16 + fg * 4 + r) * 64 +
                    (((j * 2 + (fr >> 3)) ^ ((fg * 4 + r) & 7)) << 3) + (fr & 7)] = f2bf(p);
        }
      }
    }

    // ---- PV + row-sum (ones column); V waited by compiler-inserted vmcnt
    __builtin_amdgcn_s_setprio(1);
#pragma unroll
    for (int i = 0; i < 2; ++i) {
#pragma unroll
      for (int ks = 0; ks < 2; ++ks) {
        const short8 pa = *(const short8*)&Plds[wid][(i * 16 + fr) * 64 +
                                                     (((ks * 4 + fg) ^ xsw) << 3)];
#pragma unroll
        for (int jd = 0; jd < 4; ++jd)
          o[i][jd] = __builtin_amdgcn_mfma_f32_16x16x32_bf16(pa, vreg[ks][jd], o[i][jd], 0, 0, 0);
        ol[i] = __builtin_amdgcn_mfma_f32_16x16x32_bf16(pa, ones, ol[i], 0, 0, 0);
      }
    }
    __builtin_amdgcn_s_setprio(0);
  }

  asm volatile("s_waitcnt vmcnt(0)" ::: "memory");  // drain dangling dummy stages

  // ---- epilogue: ctx[b*2048 + row][h*64 + d] = O / l
#pragma unroll
  for (int i = 0; i < 2; ++i) {
#pragma unroll
    for (int r = 0; r < 4; ++r) {
      const float inv = 1.0f / ol[i][r];
      unsigned short* cp = ctx + (size_t)(b * 2048 + qtp * 128 + i * 64 + wid * 16 +
                                          fg * 4 + r) * 512 + h * 64;
#pragma unroll
      for (int jd = 0; jd < 4; ++jd) cp[jd * 16 + fr] = f2bf(o[i][jd][r] * inv);
    }
  }
}

// ---------------------------------------------------------------------------
// Conversions
// ---------------------------------------------------------------------------
__global__ void f32_to_bf16_k(const float* __restrict__ in, unsigned short* __restrict__ out,
                              int n4) {
  const int i = blockIdx.x * 256 + threadIdx.x;
  if (i < n4) {
    const float4 v = ((const float4*)in)[i];
    us4 o;
    o[0] = f2bf(v.x);
    o[1] = f2bf(v.y);
    o[2] = f2bf(v.z);
    o[3] = f2bf(v.w);
    ((us4*)out)[i] = o;
  }
}

// out[n][k] = bf16(in[k][n]) for 512x512 weight (x @ W -> C = A * W^T form)
__global__ void transpose_w_k(const float* __restrict__ in, unsigned short* __restrict__ out) {
  const int idx = blockIdx.x * 256 + threadIdx.x;
  const int row = idx >> 9, col = idx & 511;
  out[idx] = f2bf(in[col * 512 + row]);
}

// ---------------------------------------------------------------------------
extern "C" void kernel_launch(void* const* d_in, const int* in_sizes, int n_in,
                              void* d_out, int out_size, void* d_ws, size_t ws_size,
                              hipStream_t stream) {
  (void)in_sizes; (void)n_in; (void)out_size; (void)ws_size;
  const float* x = (const float*)d_in[0];
  const float* wqk = (const float*)d_in[1];
  const float* wv = (const float*)d_in[2];
  const float* bv = (const float*)d_in[3];
  const float* wp = (const float*)d_in[4];
  const float* bp = (const float*)d_in[5];
  // d_in[6] (mask) unused: mask computed analytically in-kernel.

  char* ws = (char*)d_ws;
  unsigned short* x_bf   = (unsigned short*)(ws + 0);                    //   8 MB [8192][512]
  unsigned short* wqk_bf = (unsigned short*)(ws + (size_t)8 * 1048576);  //   8 MB [8192][512]
  unsigned short* wv_t   = (unsigned short*)(ws + (size_t)16 * 1048576); // 0.5 MB [512][512]
  unsigned short* wp_t   = (unsigned short*)(ws + (size_t)17 * 1048576); // 0.5 MB [512][512]
  unsigned short* qk_bf  = (unsigned short*)(ws + (size_t)18 * 1048576); // 128 MB [8192][8192]
  unsigned short* v_t    = (unsigned short*)(ws + (size_t)146 * 1048576);//   8 MB [2048][2048]
  unsigned short* ctx_bf = (unsigned short*)(ws + (size_t)154 * 1048576);//   8 MB [8192][512]

  f32_to_bf16_k<<<4096, 256, 0, stream>>>(x, x_bf, 1048576);
  f32_to_bf16_k<<<4096, 256, 0, stream>>>(wqk, wqk_bf, 1048576);
  transpose_w_k<<<1024, 256, 0, stream>>>(wv, wv_t);
  transpose_w_k<<<1024, 256, 0, stream>>>(wp, wp_t);

  // QK = x @ w_qk^T : [8192][8192] bf16 (cols 0..4095 = Q, 4096..8191 = K)
  gemm_bt<0><<<dim3(64, 64), 256, 0, stream>>>(x_bf, wqk_bf, qk_bf, nullptr, 8192, 8192, 512);
  // V = x @ w_v + b_v, stored transposed [ (b*8+h)*64+d ][ t ]
  gemm_bt<1><<<dim3(64, 4), 256, 0, stream>>>(x_bf, wv_t, v_t, bv, 8192, 512, 512);

  flash_attn<<<512, 256, 0, stream>>>(qk_bf, v_t, ctx_bf);

  // out = ctx @ w_proj + b_proj (f32)
  gemm_bt<2><<<dim3(64, 4), 256, 0, stream>>>(ctx_bf, wp_t, d_out, bp, 8192, 512, 512);
}

// Round 7
// 356.587 us; speedup vs baseline: 1.0050x; 1.0050x over previous
//
#include <hip/hip_runtime.h>
#include <stdint.h>

// ---------------------------------------------------------------------------
// LogSparse attention (B=4, T=2048, E=512, H=8, head_dim=64, q/k width e=512)
//   0) convert x, w_qk to bf16; transpose+convert w_v, w_proj to [N][K] bf16
//   1) QK = x @ w_qk^T           (bf16 MFMA GEMM, C bf16 [8192][8192])
//   2) V  = x @ w_v + b_v        (bf16 MFMA GEMM, stored transposed [b,h,d,t])
//   3) flash attention, analytic log-sparse mask -> ctx bf16 [8192][512]
//      - 64-row q-tiles, 2 waves x 32 rows, 128 threads, 1024 blocks
//      - 40 KB LDS/block -> 4 blocks/CU (TLP from independent blocks)
//      - K: 4 x 8KB chunk buffers, depth-3 counted-vmcnt pipeline
//      - no-max softmax (data-safe), row-sum via all-ones MFMA column
//      - V global->reg (issued phase 4, aged 3 phases), P via swizzled LDS
//   4) out = ctx @ w_proj + b_proj (f32 out)
// ---------------------------------------------------------------------------

typedef __attribute__((ext_vector_type(8))) short short8;
typedef __attribute__((ext_vector_type(4))) float f32x4;
typedef __attribute__((ext_vector_type(4))) unsigned short us4;

__device__ __forceinline__ f32x4 fzero4() { f32x4 z = {0.f, 0.f, 0.f, 0.f}; return z; }

__device__ __forceinline__ unsigned short f2bf(float f) {  // RNE f32->bf16
  unsigned u = __float_as_uint(f);
  u += 0x7fff + ((u >> 16) & 1);
  return (unsigned short)(u >> 16);
}

__device__ __forceinline__ void gload_lds16(const void* g, void* l) {
  __builtin_amdgcn_global_load_lds((const __attribute__((address_space(1))) void*)g,
                                   (__attribute__((address_space(3))) void*)l, 16, 0, 0);
}

// bijective XCD swizzle (nwg % 8 == 0 for all our grids)
__device__ __forceinline__ int xcd_swizzle(int flat, int nwg) {
  const int cpx = nwg >> 3;
  return (flat & 7) * cpx + (flat >> 3);
}

// ---------------------------------------------------------------------------
// GEMM: C[M,N] = A[M,K] * B[N,K]^T  (A,B bf16 row-major, K-contiguous)
// 128x128 tile, BK=32, 256 threads (4 waves, 2x2), 16x16x32 bf16 MFMA.
// EPI 0: C bf16 row-major, no bias
// EPI 1: V epilogue: bf16, +bias, stored transposed V_t[(b*512+col)][t]
// EPI 2: C f32 row-major, +bias
// ---------------------------------------------------------------------------
template <int EPI>
__global__ __launch_bounds__(256, 2) void gemm_bt(const unsigned short* __restrict__ A,
                                                  const unsigned short* __restrict__ B,
                                                  void* __restrict__ Cout,
                                                  const float* __restrict__ bias,
                                                  int M, int N, int K) {
  __shared__ unsigned short As[128 * 32];
  __shared__ unsigned short Bs[128 * 32];
  const int tid = threadIdx.x;
  const int wid = tid >> 6;
  const int lane = tid & 63;
  const int wm = wid >> 1, wn = wid & 1;
  const int nbx = (M + 127) / 128;
  const int sw = xcd_swizzle(blockIdx.y * gridDim.x + blockIdx.x, gridDim.x * gridDim.y);
  const long m0 = (long)(sw % nbx) * 128;
  const long n0 = (long)(sw / nbx) * 128;

  f32x4 acc[4][4];
#pragma unroll
  for (int i = 0; i < 4; ++i)
#pragma unroll
    for (int j = 0; j < 4; ++j) acc[i][j] = fzero4();

  const int lrow = tid >> 2;          // 0..63
  const int lcol = (tid & 3) * 8;     // 0,8,16,24
  const unsigned short* Ag = A + (m0 + lrow) * (long)K + lcol;
  const unsigned short* Bg = B + (n0 + lrow) * (long)K + lcol;
  unsigned short* Asl = As + tid * 8;
  unsigned short* Bsl = Bs + tid * 8;
  const long K64 = (long)64 * K;

  const int fr = lane & 15;
  const int fk = (lane >> 4) * 8;

  for (int k0 = 0; k0 < K; k0 += 32) {
    gload_lds16(Ag + k0, Asl);
    gload_lds16(Ag + K64 + k0, Asl + 2048);
    gload_lds16(Bg + k0, Bsl);
    gload_lds16(Bg + K64 + k0, Bsl + 2048);
    __syncthreads();
    short8 af[4], bfr[4];
#pragma unroll
    for (int i = 0; i < 4; ++i) af[i] = *(const short8*)&As[(wm * 64 + i * 16 + fr) * 32 + fk];
#pragma unroll
    for (int j = 0; j < 4; ++j) bfr[j] = *(const short8*)&Bs[(wn * 64 + j * 16 + fr) * 32 + fk];
#pragma unroll
    for (int i = 0; i < 4; ++i)
#pragma unroll
      for (int j = 0; j < 4; ++j)
        acc[i][j] = __builtin_amdgcn_mfma_f32_16x16x32_bf16(af[i], bfr[j], acc[i][j], 0, 0, 0);
    __syncthreads();
  }

  const int fg = lane >> 4;
#pragma unroll
  for (int i = 0; i < 4; ++i) {
#pragma unroll
    for (int j = 0; j < 4; ++j) {
      const long row0 = m0 + wm * 64 + i * 16 + fg * 4;  // +r
      const long col = n0 + wn * 64 + j * 16 + fr;
      if (EPI == 0) {
        unsigned short* C = (unsigned short*)Cout;
#pragma unroll
        for (int r = 0; r < 4; ++r) C[(row0 + r) * (long)N + col] = f2bf(acc[i][j][r]);
      } else if (EPI == 1) {
        unsigned short* C = (unsigned short*)Cout;
        const float bs = bias[col];
        const int b_ = (int)(row0 >> 11);
        const int t0 = (int)(row0 & 2047);
        us4 pk;
#pragma unroll
        for (int r = 0; r < 4; ++r) pk[r] = f2bf(acc[i][j][r] + bs);
        *(us4*)&C[((size_t)(b_ * 512 + col)) * 2048 + t0] = pk;  // [b,h,d][t]
      } else {
        float* C = (float*)Cout;
        const float bs = bias[col];
#pragma unroll
        for (int r = 0; r < 4; ++r) C[(row0 + r) * (long)N + col] = acc[i][j][r] + bs;
      }
    }
  }
}

// ---------------------------------------------------------------------------
// Flash attention, log-sparse mask. 1024 blocks, 128 threads (2 waves).
// blk -> (bh = blk&31, qt = 31-(blk>>5)): 64 q-rows, longest job first.
// Wave w owns rows w*32..w*32+31 as 2 i-groups of 16; softmax in-register.
// K: 4 x 8KB chunk buffers [64 keys][64 e], XOR-swizzled (pre-swizzled
// global src), depth-3 counted-vmcnt pipeline, 8 phases/ktile.
// V: global->reg issued at phase 4. P: wave-private swizzled LDS.
// No-max softmax; row-sum l accumulated via all-ones MFMA B operand.
// ---------------------------------------------------------------------------
#define STAGE_CHUNK(BUF, GC)                                                  \
  do {                                                                        \
    const unsigned short* _src = Kg + (size_t)((GC) >> 3) * (64 * 8192) + ((GC) & 7) * 64; \
    gload_lds16(_src,                       &Kb[BUF][tid * 8]);               \
    gload_lds16(_src + (size_t)16 * 8192,   &Kb[BUF][1024 + tid * 8]);        \
    gload_lds16(_src + (size_t)32 * 8192,   &Kb[BUF][2048 + tid * 8]);        \
    gload_lds16(_src + (size_t)48 * 8192,   &Kb[BUF][3072 + tid * 8]);        \
  } while (0)

#define QK_COMPUTE(BUF, KS0)                                                  \
  __builtin_amdgcn_s_setprio(1);                                              \
  _Pragma("unroll") for (int e = 0; e < 2; ++e) {                             \
    _Pragma("unroll") for (int j = 0; j < 4; ++j) {                           \
      const short8 bfr = *(const short8*)&Kb[BUF][(j * 16 + fr) * 64 +        \
                                                  (((e * 4 + fg) ^ xsw) << 3)]; \
      s[0][j] = __builtin_amdgcn_mfma_f32_16x16x32_bf16(qreg[0][(KS0) + e],   \
                                                        bfr, s[0][j], 0, 0, 0); \
      s[1][j] = __builtin_amdgcn_mfma_f32_16x16x32_bf16(qreg[1][(KS0) + e],   \
                                                        bfr, s[1][j], 0, 0, 0); \
    }                                                                         \
  }                                                                           \
  __builtin_amdgcn_s_setprio(0);

// one phase: wait(N), barrier, stage chunk C+3 (clamped), compute chunk C
#define PHASE(N, C)                                                           \
  do {                                                                        \
    asm volatile("s_waitcnt vmcnt(" #N ")" ::: "memory");                     \
    asm volatile("s_barrier" ::: "memory");                                   \
    int _g3 = kt * 8 + (C) + 3;                                               \
    if (_g3 >= nG) _g3 = nG - 1;                                              \
    STAGE_CHUNK(((C) + 3) & 3, _g3);                                          \
    QK_COMPUTE((C) & 3, (C) * 2);                                             \
  } while (0)

__global__ __launch_bounds__(128, 2) void flash_attn(const unsigned short* __restrict__ QK,
                                                     const unsigned short* __restrict__ Vt,
                                                     unsigned short* __restrict__ ctx) {
  __shared__ unsigned short Kb[4][64 * 64];    // 4 x 8 KB
  __shared__ unsigned short Plds[2][32 * 64];  // 8 KB, per-wave

  const int tid = threadIdx.x, wid = tid >> 6, lane = tid & 63;
  const int fr = lane & 15, fg = lane >> 4;
  const int xsw = fr & 7;
  const int blk = blockIdx.x;
  const int qt = 31 - (blk >> 5);  // longest-first
  const int bh = blk & 31;
  const int b = bh >> 3, h = bh & 7;
  const int nG = (qt + 1) * 8;

  // ---- Q fragments -> registers: 2 i-groups x 16 e-steps (128 VGPR)
  short8 qreg[2][16];
  {
    const unsigned short* qp =
        QK + (size_t)(b * 2048 + qt * 64 + wid * 32 + fr) * 8192 + h * 512 + fg * 8;
#pragma unroll
    for (int i = 0; i < 2; ++i)
#pragma unroll
      for (int e = 0; e < 16; ++e)
        qreg[i][e] = *(const short8*)(qp + (size_t)i * 16 * 8192 + e * 32);
  }

  // ---- mask bitmaps (bit r*4+j), per i-group (rows 16 apart -> differ mod 64)
  unsigned m_gen[2], m_t0[2], m_diag[2];
#pragma unroll
  for (int i = 0; i < 2; ++i) {
    const int lrow = wid * 32 + i * 16 + fg * 4;  // row within 64-row tile
    m_gen[i] = 0xFFFFu; m_t0[i] = 0xFFFFu; m_diag[i] = 0u;
    if (qt <= 5) {  // rows < 384: plain causal
#pragma unroll
      for (int r = 0; r < 4; ++r)
#pragma unroll
        for (int j = 0; j < 4; ++j)
          if (j * 16 + fr <= lrow + r) m_diag[i] |= 1u << (r * 4 + j);
    } else {
      m_gen[i] = 0; m_t0[i] = 0;
      const unsigned long long SBITS = 0x20002022FFull;  // t in {0..7,9,13,21,37}
#pragma unroll
      for (int r = 0; r < 4; ++r) {
        const int irow = qt * 64 + lrow + r;
#pragma unroll
        for (int j = 0; j < 4; ++j) {
          const int c = j * 16 + fr;
          const int t = (irow - c) & 63;
          const unsigned g = (unsigned)((SBITS >> t) & 1ull);
          const unsigned bit = 1u << (r * 4 + j);
          if (g) m_gen[i] |= bit;
          if ((c + t >= 5) ? (g != 0) : (t >= 1)) m_t0[i] |= bit;  // terminal rule
          if (g && c <= lrow + r) m_diag[i] |= bit;
        }
      }
    }
  }

  f32x4 o[2][4], ol[2];
#pragma unroll
  for (int i = 0; i < 2; ++i) {
    ol[i] = fzero4();
#pragma unroll
    for (int j = 0; j < 4; ++j) o[i][j] = fzero4();
  }

  short8 ones;
#pragma unroll
  for (int z = 0; z < 8; ++z) ones[z] = (short)0x3F80;  // bf16 1.0

  // ---- K staging base (pre-swizzled global source; LDS dest linear)
  // chunk = [64 keys][64 e]; round covers 16 rows, 8 x 16B slots per row
  const int srow = tid >> 3;                         // 0..15 row within round
  const int sslot = (tid & 7) ^ (srow & 7);          // inverse-swizzled slot
  const unsigned short* Kg =
      QK + (size_t)(b * 2048 + srow) * 8192 + 4096 + h * 512 + sslot * 8;

  // prologue: chunks 0,1,2 -> buffers 0,1,2 (depth-3)
  STAGE_CHUNK(0, 0);
  STAGE_CHUNK(1, 1);
  STAGE_CHUNK(2, 2);

  for (int kt = 0; kt <= qt; ++kt) {
    f32x4 s[2][4];
#pragma unroll
    for (int i = 0; i < 2; ++i)
#pragma unroll
      for (int j = 0; j < 4; ++j) s[i][j] = fzero4();
    short8 vreg[2][4];

    PHASE(8, 0);
    PHASE(8, 1);
    PHASE(8, 2);
    PHASE(8, 3);

    // ---- phase 4: V loads first (pinned), then stage, then compute
    asm volatile("s_waitcnt vmcnt(8)" ::: "memory");
    asm volatile("s_barrier" ::: "memory");
#pragma unroll
    for (int ks = 0; ks < 2; ++ks)
#pragma unroll
      for (int jd = 0; jd < 4; ++jd)
        vreg[ks][jd] = *(const short8*)(Vt + (size_t)(bh * 64 + jd * 16 + fr) * 2048 +
                                        kt * 64 + ks * 32 + fg * 8);
    __builtin_amdgcn_sched_barrier(0);  // keep V-issue before the stage below
    {
      int _g3 = kt * 8 + 7;
      if (_g3 >= nG) _g3 = nG - 1;
      STAGE_CHUNK(3, _g3);
    }
    QK_COMPUTE(0, 8);

    PHASE(16, 5);
    PHASE(16, 6);
    PHASE(12, 7);

    // ---- no-max softmax: P = exp2(s * scale * log2e), masked -> 0
#pragma unroll
    for (int i = 0; i < 2; ++i) {
      unsigned mm = (kt == 0) ? m_t0[i] : m_gen[i];
      if (kt == qt) mm &= m_diag[i];
#pragma unroll
      for (int r = 0; r < 4; ++r) {
#pragma unroll
        for (int j = 0; j < 4; ++j) {
          float v = s[i][j][r] * 0.18033688f;  // 0.125 * log2(e)
          v = ((mm >> (r * 4 + j)) & 1u) ? v : -1e30f;
          const float p = __builtin_amdgcn_exp2f(v);
          Plds[wid][(i * 16 + fg * 4 + r) * 64 +
                    (((j * 2 + (fr >> 3)) ^ ((fg * 4 + r) & 7)) << 3) + (fr & 7)] = f2bf(p);
        }
      }
    }

    // ---- PV + row-sum (ones column); V waited by compiler-inserted vmcnt
    __builtin_amdgcn_s_setprio(1);
#pragma unroll
    for (int i = 0; i < 2; ++i) {
#pragma unroll
      for (int ks = 0; ks < 2; ++ks) {
        const short8 pa = *(const short8*)&Plds[wid][(i * 16 + fr) * 64 +
                                                     (((ks * 4 + fg) ^ xsw) << 3)];
#pragma unroll
        for (int jd = 0; jd < 4; ++jd)
          o[i][jd] = __builtin_amdgcn_mfma_f32_16x16x32_bf16(pa, vreg[ks][jd], o[i][jd], 0, 0, 0);
        ol[i] = __builtin_amdgcn_mfma_f32_16x16x32_bf16(pa, ones, ol[i], 0, 0, 0);
      }
    }
    __builtin_amdgcn_s_setprio(0);
  }

  asm volatile("s_waitcnt vmcnt(0)" ::: "memory");  // drain dangling dummy stages

  // ---- epilogue: ctx[b*2048 + row][h*64 + d] = O / l
#pragma unroll
  for (int i = 0; i < 2; ++i) {
#pragma unroll
    for (int r = 0; r < 4; ++r) {
      const float inv = 1.0f / ol[i][r];
      unsigned short* cp = ctx + (size_t)(b * 2048 + qt * 64 + wid * 32 + i * 16 +
                                          fg * 4 + r) * 512 + h * 64;
#pragma unroll
      for (int jd = 0; jd < 4; ++jd) cp[jd * 16 + fr] = f2bf(o[i][jd][r] * inv);
    }
  }
}

// ---------------------------------------------------------------------------
// Conversions
// ---------------------------------------------------------------------------
__global__ void f32_to_bf16_k(const float* __restrict__ in, unsigned short* __restrict__ out,
                              int n4) {
  const int i = blockIdx.x * 256 + threadIdx.x;
  if (i < n4) {
    const float4 v = ((const float4*)in)[i];
    us4 o;
    o[0] = f2bf(v.x);
    o[1] = f2bf(v.y);
    o[2] = f2bf(v.z);
    o[3] = f2bf(v.w);
    ((us4*)out)[i] = o;
  }
}

// out[n][k] = bf16(in[k][n]) for 512x512 weight (x @ W -> C = A * W^T form)
__global__ void transpose_w_k(const float* __restrict__ in, unsigned short* __restrict__ out) {
  const int idx = blockIdx.x * 256 + threadIdx.x;
  const int row = idx >> 9, col = idx & 511;
  out[idx] = f2bf(in[col * 512 + row]);
}

// ---------------------------------------------------------------------------
extern "C" void kernel_launch(void* const* d_in, const int* in_sizes, int n_in,
                              void* d_out, int out_size, void* d_ws, size_t ws_size,
                              hipStream_t stream) {
  (void)in_sizes; (void)n_in; (void)out_size; (void)ws_size;
  const float* x = (const float*)d_in[0];
  const float* wqk = (const float*)d_in[1];
  const float* wv = (const float*)d_in[2];
  const float* bv = (const float*)d_in[3];
  const float* wp = (const float*)d_in[4];
  const float* bp = (const float*)d_in[5];
  // d_in[6] (mask) unused: mask computed analytically in-kernel.

  char* ws = (char*)d_ws;
  unsigned short* x_bf   = (unsigned short*)(ws + 0);                    //   8 MB [8192][512]
  unsigned short* wqk_bf = (unsigned short*)(ws + (size_t)8 * 1048576);  //   8 MB [8192][512]
  unsigned short* wv_t   = (unsigned short*)(ws + (size_t)16 * 1048576); // 0.5 MB [512][512]
  unsigned short* wp_t   = (unsigned short*)(ws + (size_t)17 * 1048576); // 0.5 MB [512][512]
  unsigned short* qk_bf  = (unsigned short*)(ws + (size_t)18 * 1048576); // 128 MB [8192][8192]
  unsigned short* v_t    = (unsigned short*)(ws + (size_t)146 * 1048576);//   8 MB [2048][2048]
  unsigned short* ctx_bf = (unsigned short*)(ws + (size_t)154 * 1048576);//   8 MB [8192][512]

  f32_to_bf16_k<<<4096, 256, 0, stream>>>(x, x_bf, 1048576);
  f32_to_bf16_k<<<4096, 256, 0, stream>>>(wqk, wqk_bf, 1048576);
  transpose_w_k<<<1024, 256, 0, stream>>>(wv, wv_t);
  transpose_w_k<<<1024, 256, 0, stream>>>(wp, wp_t);

  // QK = x @ w_qk^T : [8192][8192] bf16 (cols 0..4095 = Q, 4096..8191 = K)
  gemm_bt<0><<<dim3(64, 64), 256, 0, stream>>>(x_bf, wqk_bf, qk_bf, nullptr, 8192, 8192, 512);
  // V = x @ w_v + b_v, stored transposed [ (b*8+h)*64+d ][ t ]
  gemm_bt<1><<<dim3(64, 4), 256, 0, stream>>>(x_bf, wv_t, v_t, bv, 8192, 512, 512);

  flash_attn<<<1024, 128, 0, stream>>>(qk_bf, v_t, ctx_bf);

  // out = ctx @ w_proj + b_proj (f32)
  gemm_bt<2><<<dim3(64, 4), 256, 0, stream>>>(ctx_bf, wp_t, d_out, bp, 8192, 512, 512);
}